// Round 6
// baseline (547.872 us; speedup 1.0000x reference)
//
#include <hip/hip_runtime.h>
#include <stdint.h>

#define N_NODES 100000
#define N_EDGES 3200000
#define NFEAT 512
#define NHID 256
#define MPAD 100096  // 782 * 128

typedef __attribute__((ext_vector_type(8))) short bf16x8_t;  // 8 bf16 in 4 VGPRs
typedef __attribute__((ext_vector_type(4))) unsigned short u16x4_t;
typedef __attribute__((ext_vector_type(4))) float f32x4_t;

#define RFL(x) __builtin_amdgcn_readfirstlane(x)

__device__ inline unsigned short f2bf(float f) {
  union { float f; uint32_t u; } x; x.f = f;
  uint32_t r = x.u + 0x7fffu + ((x.u >> 16) & 1u);  // RNE
  return (unsigned short)(r >> 16);
}
__device__ inline float b2f(unsigned short u) {
  union { uint32_t u; float f; } x; x.u = ((uint32_t)u) << 16;
  return x.f;
}

// ---- prep: W1 [512][256] -> W1T bf16 [256][512]; W2 [256][256] -> W2T bf16 [256][256]
__global__ void prep_k(const float* __restrict__ W1, const float* __restrict__ W2,
                       unsigned short* __restrict__ W1T, unsigned short* __restrict__ W2T) {
  int i = blockIdx.x * 256 + threadIdx.x;
  if (i < NFEAT * NHID) {
    int k = i >> 8, n = i & 255;
    W1T[n * NFEAT + k] = f2bf(W1[i]);
  } else {
    int j = i - NFEAT * NHID;
    int k = j >> 8, n = j & 255;
    W2T[n * NHID + k] = f2bf(W2[j]);
  }
}

// ---- row_ptr[r] = lower_bound(edge_row, r), r in [0, N_NODES]
__global__ void rowptr_k(const int* __restrict__ erow, int* __restrict__ rowptr) {
  int r = blockIdx.x * 256 + threadIdx.x;
  if (r > N_NODES) return;
  int lo = 0, hi = N_EDGES;
  while (lo < hi) {
    int mid = (lo + hi) >> 1;
    if (erow[mid] < r) lo = mid + 1; else hi = mid;
  }
  rowptr[r] = lo;
}

// ---- GEMM C[M][256] (bf16 out) = A[M][K] @ BT[256][K]^T
// BM=128, BN=256, BK=64, 512 threads (8 waves, 2x4), LDS 48KB, XOR-swizzled.
template <bool A_FP32>
__global__ __launch_bounds__(512) void gemm_bt2(const void* __restrict__ Ap,
                                                const unsigned short* __restrict__ BT,
                                                unsigned short* __restrict__ C,
                                                int K, int Mreal) {
  __shared__ __align__(16) unsigned short As[128 * 64];  // 16 KB
  __shared__ __align__(16) unsigned short Bs[256 * 64];  // 32 KB
  const int tid = threadIdx.x;
  const int lane = tid & 63, wid = tid >> 6;
  const int wm = wid >> 2, wn = wid & 3;  // 2 x 4 waves, each 64x64 out
  const int m0 = blockIdx.x * 128;
  const int lrow = lane & 15, lhi = lane >> 4;

  f32x4_t acc[4][4] = {};

  const int nt = K >> 6;
  for (int t = 0; t < nt; ++t) {
    __syncthreads();  // WAR
    if constexpr (A_FP32) {
      const float* A = (const float*)Ap;
      const int rr = tid >> 4;
      const int kq = (tid & 15) << 2;
#pragma unroll
      for (int round = 0; round < 4; ++round) {
        int row = rr + (round << 5);
        int grow = m0 + row; grow = grow < Mreal ? grow : Mreal - 1;
        const f32x4_t v = __builtin_nontemporal_load(
            (const f32x4_t*)(A + (size_t)grow * K + (t << 6) + kq));
        ushort4 b4;
        b4.x = f2bf(v.x); b4.y = f2bf(v.y); b4.z = f2bf(v.z); b4.w = f2bf(v.w);
        *(ushort4*)&As[(row << 6) + (kq ^ ((row & 7) << 3))] = b4;
      }
    } else {
      const unsigned short* A = (const unsigned short*)Ap;
      const int Lrow = tid >> 3;
      const int Lc = (tid & 7) << 4;
#pragma unroll
      for (int round = 0; round < 2; ++round) {
        int row = Lrow + (round << 6);
        int srcc = Lc ^ ((row & 7) << 4);
        const char* g = (const char*)(A + (size_t)(m0 + row) * K + (t << 6)) + srcc;
        __builtin_amdgcn_global_load_lds(
            (const __attribute__((address_space(1))) void*)g,
            (__attribute__((address_space(3))) void*)((char*)As + tid * 16 + (round << 13)),
            16, 0, 0);
      }
    }
    {
      const int Lrow = tid >> 3;
      const int Lc = (tid & 7) << 4;
#pragma unroll
      for (int round = 0; round < 4; ++round) {
        int row = Lrow + (round << 6);
        int srcc = Lc ^ ((row & 7) << 4);
        const char* g = (const char*)(BT + (size_t)row * K + (t << 6)) + srcc;
        __builtin_amdgcn_global_load_lds(
            (const __attribute__((address_space(1))) void*)g,
            (__attribute__((address_space(3))) void*)((char*)Bs + tid * 16 + (round << 13)),
            16, 0, 0);
      }
    }
    asm volatile("s_waitcnt vmcnt(0)" ::: "memory");
    __syncthreads();  // RAW

#pragma unroll
    for (int ks = 0; ks < 2; ++ks) {
      bf16x8_t af[4], bfr[4];
      const int cu = (ks << 5) + (lhi << 3);
#pragma unroll
      for (int mf = 0; mf < 4; ++mf) {
        int row = (wm << 6) + (mf << 4) + lrow;
        af[mf] = *(const bf16x8_t*)&As[(row << 6) + (cu ^ ((row & 7) << 3))];
      }
#pragma unroll
      for (int nf = 0; nf < 4; ++nf) {
        int row = (wn << 6) + (nf << 4) + lrow;
        bfr[nf] = *(const bf16x8_t*)&Bs[(row << 6) + (cu ^ ((row & 7) << 3))];
      }
#pragma unroll
      for (int mf = 0; mf < 4; ++mf)
#pragma unroll
        for (int nf = 0; nf < 4; ++nf)
          acc[mf][nf] = __builtin_amdgcn_mfma_f32_16x16x32_bf16(af[mf], bfr[nf], acc[mf][nf], 0, 0, 0);
    }
  }

#pragma unroll
  for (int mf = 0; mf < 4; ++mf)
#pragma unroll
    for (int nf = 0; nf < 4; ++nf)
#pragma unroll
      for (int j = 0; j < 4; ++j) {
        int gm = m0 + (wm << 6) + (mf << 4) + (lhi << 2) + j;
        int gn = (wn << 6) + (nf << 4) + lrow;
        C[(size_t)gm * 256 + gn] = f2bf(acc[mf][nf][j]);
      }
}

// ======== half-feature paired-edge gather ========
// Per pass: 128 cols (256 B/row). lanes 0-31 take even edge, 32-63 odd edge;
// lane owns 4 cols (8 B). Xb must be pre-offset by the pass byte offset.
// Source rows are 512 B apart (full 256-col rows).
#define LOADP4(V, W, EB)                                             \
  _Pragma("unroll")                                                  \
  for (int q = 0; q < 4; ++q) {                                      \
    uint32_t ce = (uint32_t)RFL(ecol[(EB) + 2 * q]);                 \
    uint32_t co = (uint32_t)RFL(ecol[(EB) + 2 * q + 1]);             \
    uint32_t ue = RFL(__float_as_uint(ew[(EB) + 2 * q]));            \
    uint32_t uo = RFL(__float_as_uint(ew[(EB) + 2 * q + 1]));        \
    uint32_t cv = lo ? ce : co;                                      \
    W[q] = __uint_as_float(lo ? ue : uo);                            \
    V[q] = *(const u16x4_t*)(Xb + (((size_t)cv << 9) + c8));         \
  }
#define CONSP4(V, W)                                                 \
  _Pragma("unroll")                                                  \
  for (int q = 0; q < 4; ++q)                                        \
    _Pragma("unroll")                                                \
    for (int j = 0; j < 4; ++j)                                      \
      f[j] += W[q] * b2f(V[q][j]);

#define GATHER_ROW()                                                 \
  u16x4_t va[4], vb[4]; float wa[4], wb[4];                          \
  if (e + 8 <= e1) {                                                 \
    LOADP4(va, wa, e);                                               \
    for (; e + 24 <= e1; e += 16) {                                  \
      LOADP4(vb, wb, e + 8);                                         \
      CONSP4(va, wa);                                                \
      LOADP4(va, wa, e + 16);                                        \
      CONSP4(vb, wb);                                                \
    }                                                                \
    if (e + 16 <= e1) {                                              \
      LOADP4(vb, wb, e + 8);                                         \
      CONSP4(va, wa);                                                \
      CONSP4(vb, wb);                                                \
      e += 16;                                                       \
    } else { CONSP4(va, wa); e += 8; }                               \
  }                                                                  \
  for (; e < e1; ++e) {  /* remainder: half-wave predicated */       \
    uint32_t c_ = (uint32_t)RFL(ecol[e]);                            \
    float w_ = __uint_as_float(RFL(__float_as_uint(ew[e])));         \
    u16x4_t v_ = *(const u16x4_t*)(Xb + (((size_t)c_ << 9) + c8));   \
    float wv_ = lo ? w_ : 0.0f;                                      \
    _Pragma("unroll")                                                \
    for (int j = 0; j < 4; ++j) f[j] += wv_ * b2f(v_[j]);            \
  }                                                                  \
  _Pragma("unroll")                                                  \
  for (int j = 0; j < 4; ++j) f[j] += __shfl_xor(f[j], 32);

// ---- SpMM1 half-pass P: cols [P*128, P*128+128). + bias + relu + dropout -> H half.
template <int P>
__global__ __launch_bounds__(256) void spmm1_h(const unsigned short* __restrict__ XW1,
                                               const int* __restrict__ rowptr,
                                               const int* __restrict__ ecol,
                                               const float* __restrict__ ew,
                                               const float* __restrict__ b1,
                                               const float* __restrict__ du,
                                               unsigned short* __restrict__ H) {
  const int lane = threadIdx.x & 63, wid = threadIdx.x >> 6;
  const int r = blockIdx.x * 4 + wid;
  const bool lo = lane < 32;
  const int g = lane & 31;
  const uint32_t c8 = (uint32_t)g << 3;  // byte offset of lane's 4 bf16 in the half-row
  const int g4 = g << 2;
  if (r >= N_NODES) {  // pad rows: zero so GEMM2 reads clean zeros
    if (lo) {
      ushort4 z; z.x = z.y = z.z = z.w = 0;
      *(ushort4*)&H[(size_t)r * 256 + P * 128 + g4] = z;
    }
    return;
  }
  const char* Xb = (const char*)XW1 + P * 256;
  float f[4] = {};
  int e  = RFL(rowptr[r]);
  const int e1 = RFL(rowptr[r + 1]);
  GATHER_ROW();
  if (lo) {
    const int col = P * 128 + g4;
    const f32x4_t bb = *(const f32x4_t*)&b1[col];
    const f32x4_t uu = __builtin_nontemporal_load((const f32x4_t*)&du[(size_t)r * 256 + col]);
    ushort4 o;
    o.x = f2bf(fmaxf(f[0] + bb.x, 0.f) * (uu.x < 0.5f ? 2.f : 0.f));
    o.y = f2bf(fmaxf(f[1] + bb.y, 0.f) * (uu.y < 0.5f ? 2.f : 0.f));
    o.z = f2bf(fmaxf(f[2] + bb.z, 0.f) * (uu.z < 0.5f ? 2.f : 0.f));
    o.w = f2bf(fmaxf(f[3] + bb.w, 0.f) * (uu.w < 0.5f ? 2.f : 0.f));
    *(ushort4*)&H[(size_t)r * 256 + col] = o;
  }
}

// ---- SpMM2 pass 0: cols [0,128). + bias + relu -> tmp (bf16 [N][128])
__global__ __launch_bounds__(256) void spmm2_p0(const unsigned short* __restrict__ HW2,
                                                const int* __restrict__ rowptr,
                                                const int* __restrict__ ecol,
                                                const float* __restrict__ ew,
                                                const float* __restrict__ b2,
                                                unsigned short* __restrict__ tmp) {
  const int lane = threadIdx.x & 63, wid = threadIdx.x >> 6;
  const int r = blockIdx.x * 4 + wid;
  if (r >= N_NODES) return;
  const bool lo = lane < 32;
  const int g = lane & 31;
  const uint32_t c8 = (uint32_t)g << 3;
  const int g4 = g << 2;
  const char* Xb = (const char*)HW2;
  float f[4] = {};
  int e  = RFL(rowptr[r]);
  const int e1 = RFL(rowptr[r + 1]);
  GATHER_ROW();
  if (lo) {
    const f32x4_t bb = *(const f32x4_t*)&b2[g4];
    ushort4 o;
    o.x = f2bf(fmaxf(f[0] + bb.x, 0.f));
    o.y = f2bf(fmaxf(f[1] + bb.y, 0.f));
    o.z = f2bf(fmaxf(f[2] + bb.z, 0.f));
    o.w = f2bf(fmaxf(f[3] + bb.w, 0.f));
    *(ushort4*)&tmp[(size_t)r * 128 + g4] = o;
  }
}

// ---- SpMM2 pass 1: cols [128,256) + log_softmax over the full row -> out (fp32)
__global__ __launch_bounds__(256) void spmm2_p1(const unsigned short* __restrict__ HW2,
                                                const int* __restrict__ rowptr,
                                                const int* __restrict__ ecol,
                                                const float* __restrict__ ew,
                                                const float* __restrict__ b2,
                                                const unsigned short* __restrict__ tmp,
                                                float* __restrict__ out) {
  const int lane = threadIdx.x & 63, wid = threadIdx.x >> 6;
  const int r = blockIdx.x * 4 + wid;
  if (r >= N_NODES) return;
  const bool lo = lane < 32;
  const int g = lane & 31;
  const uint32_t c8 = (uint32_t)g << 3;
  const int g4 = g << 2;
  const char* Xb = (const char*)HW2 + 256;  // second 128-col half
  float f[4] = {};
  int e  = RFL(rowptr[r]);
  const int e1 = RFL(rowptr[r + 1]);
  GATHER_ROW();
  const f32x4_t bb = *(const f32x4_t*)&b2[128 + g4];
  const u16x4_t tv = *(const u16x4_t*)&tmp[(size_t)r * 128 + g4];  // half-0 v (bf16)
  float val[4];
  val[0] = lo ? fmaxf(f[0] + bb.x, 0.f) : b2f(tv[0]);
  val[1] = lo ? fmaxf(f[1] + bb.y, 0.f) : b2f(tv[1]);
  val[2] = lo ? fmaxf(f[2] + bb.z, 0.f) : b2f(tv[2]);
  val[3] = lo ? fmaxf(f[3] + bb.w, 0.f) : b2f(tv[3]);
  // full 64-lane reduction: lo lanes hold cols 128+g4.., hi lanes cols g4..
  float m = fmaxf(fmaxf(val[0], val[1]), fmaxf(val[2], val[3]));
#pragma unroll
  for (int off = 32; off > 0; off >>= 1) m = fmaxf(m, __shfl_xor(m, off));
  float s = expf(val[0] - m) + expf(val[1] - m) + expf(val[2] - m) + expf(val[3] - m);
#pragma unroll
  for (int off = 32; off > 0; off >>= 1) s += __shfl_xor(s, off);
  const float ls = m + logf(s);
  f32x4_t o;
  o.x = val[0] - ls; o.y = val[1] - ls; o.z = val[2] - ls; o.w = val[3] - ls;
  const int col = (lo ? 128 : 0) + g4;
  __builtin_nontemporal_store(o, (f32x4_t*)&out[(size_t)r * 256 + col]);
}

extern "C" void kernel_launch(void* const* d_in, const int* in_sizes, int n_in,
                              void* d_out, int out_size, void* d_ws, size_t ws_size,
                              hipStream_t stream) {
  const float* x  = (const float*)d_in[0];
  const float* W1 = (const float*)d_in[1];
  const float* b1 = (const float*)d_in[2];
  const float* W2 = (const float*)d_in[3];
  const float* b2 = (const float*)d_in[4];
  const int* erow = (const int*)d_in[5];
  const int* ecol = (const int*)d_in[6];
  const float* ew = (const float*)d_in[7];
  const float* du = (const float*)d_in[8];
  float* out = (float*)d_out;

  char* ws = (char*)d_ws;
  unsigned short* W1T = (unsigned short*)ws;                    // 262144 B
  unsigned short* W2T = (unsigned short*)(ws + 262144);         // 131072 B
  int* rowptr = (int*)(ws + 262144 + 131072);                   // 400004 B (pad to 401408)
  unsigned short* XW1 = (unsigned short*)(ws + 262144 + 131072 + 401408);  // 51249152 B (reused as HW2)
  unsigned short* H = (unsigned short*)(ws + 262144 + 131072 + 401408 + 51249152);  // 51249152 B
  unsigned short* tmp = H;  // H is dead after gemm2; reuse as spmm2's half-0 buffer

  prep_k<<<768, 256, 0, stream>>>(W1, W2, W1T, W2T);
  rowptr_k<<<392, 256, 0, stream>>>(erow, rowptr);
  gemm_bt2<true><<<782, 512, 0, stream>>>((const void*)x, W1T, XW1, NFEAT, N_NODES);
  spmm1_h<0><<<MPAD / 4, 256, 0, stream>>>(XW1, rowptr, ecol, ew, b1, du, H);
  spmm1_h<1><<<MPAD / 4, 256, 0, stream>>>(XW1, rowptr, ecol, ew, b1, du, H);
  gemm_bt2<false><<<782, 512, 0, stream>>>((const void*)H, W2T, XW1, NHID, MPAD);
  spmm2_p0<<<N_NODES / 4, 256, 0, stream>>>(XW1, rowptr, ecol, ew, b2, tmp);
  spmm2_p1<<<N_NODES / 4, 256, 0, stream>>>(XW1, rowptr, ecol, ew, b2, tmp, out);
}